// Round 12
// baseline (41046.991 us; speedup 1.0000x reference)
//
#include <hip/hip_runtime.h>

#define UNITS 65
#define SEQ   8192
#define BATCH 50
#define LW    136          // per-layer v words: [in 65 | pad 3 | h 65 | pad 3]
#define PW    (3 * LW)     // parity block words (408)

__device__ __forceinline__ float frcp(float x){ return __builtin_amdgcn_rcpf(x); }
__device__ __forceinline__ float fsigmoid(float x){ return frcp(1.0f + __expf(-x)); }
__device__ __forceinline__ float ftanh(float x){
    float e2 = __expf(2.0f * x);
    return 1.0f - 2.0f * frcp(e2 + 1.0f);
}

template<int CTRL>
__device__ __forceinline__ float dppadd(float x){
    int t = __builtin_amdgcn_update_dpp(0, __float_as_int(x), CTRL, 0xF, 0xF, true);
    return x + __int_as_float(t);
}
template<int CTRL>
__device__ __forceinline__ float dppmov(float x){
    int t = __builtin_amdgcn_update_dpp(0, __float_as_int(x), CTRL, 0xF, 0xF, true);
    return __int_as_float(t);
}
// 64-lane sum; total valid in lane 63 (proven pattern from the baseline kernel)
__device__ __forceinline__ float red64_63(float x){
    x = dppadd<0x111>(x);  // row_shr:1
    x = dppadd<0x112>(x);  // row_shr:2
    x = dppadd<0x114>(x);  // row_shr:4
    x = dppadd<0x118>(x);  // row_shr:8
    x = dppadd<0x142>(x);  // row_bcast:15
    x = dppadd<0x143>(x);  // row_bcast:31
    return x;
}
// barrier WITHOUT vmcnt drain (LDS ordering only) — globals here are block-private
__device__ __forceinline__ void bar_lds(){
    asm volatile("s_waitcnt lgkmcnt(0)\n\ts_barrier" ::: "memory");
}

// row k of concatenated [W;U] (K=130), column c
__device__ __forceinline__ float wrow(const float* W, const float* U, int k, int c){
    return (k < 65) ? W[k * 260 + c] : U[(k - 65) * 260 + c];
}

// word index of v value k: in[k] at word k (k<65); h[k-65] at word 68+(k-65)=k+3
#define VW(K) ((K) < 65 ? (K) : (K) + 3)
// broadcast word W_ of the wave's distributed f4 (lane W_>>2, comp W_&3) — W_ const
#define RLF(fv, W_) __int_as_float(__builtin_amdgcn_readlane(                   \
        __float_as_int((&(fv).x)[(W_) & 3]), (W_) >> 2))

// ---------------------------------------------------------------------------
// ROUND-12 (= round-11 resubmission; GPU never acquired).
// COLUMN-RESIDENT decomposition (leaves the U x S family whose LDS
// instruction count is provably invariant ~100-150/step — the floor that made
// rounds 1/4/5/6/10 all land at 14.4-15.2 ms).
// 256 threads = 4 waves = 1 wave/SIMD. Lane (wave w, lane L) owns column
// (unit j = 16w + (L>>2), gate = L&3) with ALL 130 weights register-resident,
// and computes it for ALL 3 layers (weights shared across layers).
// Per step per wave: 3 distributed ds_read_b128 (lane L holds v-words
// 4L..4L+3), then 130 v_readlane broadcasts feed 130 v_fmac per layer —
// v-broadcast moves from the LDS pipe to the VALU pipe. No K-split => no
// reduction tree. i/f/g/o of a unit sit in one quad => c/h via 3 quad-DPP.
// Unit-64: waves 1..3 own layer (wave-1): distributed 16-FMA partials on the
// already-loaded f4 + DPP wave-reduce. LDS insts/CU/step: ~250 -> ~30.
// ONE 4-wave barrier per step. Layer pipeline skew as before
// (layer0@t=s, layer1@t=s-1, layer2@t=s-2 -> out row s-2).
// ---------------------------------------------------------------------------

// activation + state update for one layer's regular units (all lanes).
// o-lane (gate==3) commits c and performs WRITES (uses hn_).
#define ACT(ZS, CST, ...) do {                                                 \
    float z_  = (ZS) + breg;                                                   \
    float sg_ = frcp(1.0f + __expf(-sk * z_));                                 \
    float g_  = fmaf(sk, sg_, dk);       /* quad lanes: 0:i 1:f 2:g 3:o */     \
    float gi_ = dppmov<0x00>(g_);                                              \
    float gf_ = dppmov<0x55>(g_);                                              \
    float gg_ = dppmov<0xAA>(g_);                                              \
    float cn_ = fmaf(gf_, CST, gi_ * gg_);                                     \
    float hn_ = g_ * ftanh(cn_);                                               \
    if (og) { CST = cn_; __VA_ARGS__; }                                        \
} while (0)

#define STEP(L0, L1, L2) do {                                                  \
    float* vb = lds + cur * PW;                                                \
    float* vn = lds + (cur ^ 1) * PW;                                          \
    /* early: next-x global load (wave 0 only); consumed next step */          \
    float4 nx4 = {0,0,0,0}; float nxs = 0.0f;                                  \
    if (L0) { if (wave == 0) {                                                 \
        const int tl_ = (s + 2 < SEQ) ? (s + 2) : (SEQ - 1);                   \
        if (lane < 16) nx4 = *(const float4*)(xrow + (size_t)tl_ * UNITS + 4 * lane); \
        if (lane == 16) nxs = xrow[(size_t)tl_ * UNITS + 64];                  \
    } }                                                                        \
    /* distributed v reads: ONE b128 per active layer */                       \
    float4 fv0 = {0,0,0,0}, fv1 = {0,0,0,0}, fv2 = {0,0,0,0};                  \
    if (L0) fv0 = *(const float4*)(vb + rdoff);                                \
    if (L1) fv1 = *(const float4*)(vb + LW + rdoff);                           \
    if (L2) fv2 = *(const float4*)(vb + 2 * LW + rdoff);                       \
    /* broadcast-FMA main loop: readlane -> SGPR -> fmac, 3 layers interleaved */ \
    float a0 = 0, a0b = 0, a1 = 0, a1b = 0, a2 = 0, a2b = 0;                   \
    _Pragma("unroll")                                                          \
    for (int k = 0; k < 130; ++k) {                                            \
        if (L0) { float sv_ = RLF(fv0, VW(k));                                 \
            if (k < 65) a0  = fmaf(sv_, wcol[k], a0);                          \
            else        a0b = fmaf(sv_, wcol[k], a0b); }                       \
        if (L1) { float sv_ = RLF(fv1, VW(k));                                 \
            if (k < 65) a1  = fmaf(sv_, wcol[k], a1);                          \
            else        a1b = fmaf(sv_, wcol[k], a1b); }                       \
        if (L2) { float sv_ = RLF(fv2, VW(k));                                 \
            if (k < 65) a2  = fmaf(sv_, wcol[k], a2);                          \
            else        a2b = fmaf(sv_, wcol[k], a2b); }                       \
    }                                                                          \
    /* x(s+1) write into next v0 (loaded last step); promote prefetch */       \
    if (L0) { if (wave == 0) {                                                 \
        if (lane < 16) *(float4*)(vn + 4 * lane) = xq4;                        \
        if (lane == 16) vn[64] = xqs;                                          \
        xq4 = nx4; xqs = nxs;                                                  \
    } }                                                                        \
    /* activations + h writes */                                               \
    if (L0) ACT(a0 + a0b, c_0,                                                 \
                vn[68 + j] = hn_;            /* h0 recurrence   */             \
                vn[LW + j] = hn_);           /* layer1 input    */             \
    if (L1) ACT(a1 + a1b, c_1,                                                 \
                vn[LW + 68 + j] = hn_;                                         \
                vn[2 * LW + j] = hn_);                                         \
    if (L2) ACT(a2 + a2b, c_2,                                                 \
                vn[2 * LW + 68 + j] = hn_;                                     \
                orow[(size_t)(s - 2) * UNITS + j] = hn_);                      \
    /* unit-64: wave m64+1 owns layer m64 (waves 1..3) */                      \
    {                                                                          \
        const bool a64_ = (wave == 1) ? (bool)(L0)                             \
                        : (wave == 2) ? (bool)(L1)                             \
                        : (wave == 3) ? (bool)(L2) : false;                    \
        if (a64_) {                                                            \
            float4 fvm = (m64 == 0) ? fv0 : (m64 == 1) ? fv1 : fv2;            \
            float p0 = 0, p1 = 0, p2 = 0, p3 = 0;                              \
            _Pragma("unroll")                                                  \
            for (int i = 0; i < 4; ++i) {                                      \
                float sv_ = (&fvm.x)[i];                                       \
                p0 = fmaf(sv_, w64w[i][0], p0);                                \
                p1 = fmaf(sv_, w64w[i][1], p1);                                \
                p2 = fmaf(sv_, w64w[i][2], p2);                                \
                p3 = fmaf(sv_, w64w[i][3], p3);                                \
            }                                                                  \
            p0 = red64_63(p0); p1 = red64_63(p1);                              \
            p2 = red64_63(p2); p3 = red64_63(p3);                              \
            float gi4_ = fsigmoid(p0 + b64i);                                  \
            float gf4_ = fsigmoid(p1 + b64f);                                  \
            float gg4_ = ftanh  (p2 + b64g);                                   \
            float go4_ = fsigmoid(p3 + b64o);                                  \
            float cn64_ = fmaf(gf4_, c64, gi4_ * gg4_);                        \
            float hn64_ = go4_ * ftanh(cn64_);                                 \
            if (lane == 63) {                                                  \
                c64 = cn64_;                                                   \
                vn[m64 * LW + 132] = hn64_;              /* h[64] recur */     \
                if (wave <= 2) vn[(m64 + 1) * LW + 64] = hn64_;                \
                else orow[(size_t)(s - 2) * UNITS + 64] = hn64_;               \
            }                                                                  \
        }                                                                      \
    }                                                                          \
    cur ^= 1;                                                                  \
    bar_lds();                                                                 \
} while (0)

// One block per batch element. 256 threads = 4 waves = 1 wave/SIMD (512-reg cap
// so the 130 weight floats stay register-resident).
__global__ __launch_bounds__(256, 1)
void lstm3_kernel(const float* __restrict__ x, const float* __restrict__ W,
                  const float* __restrict__ U, const float* __restrict__ b,
                  float* __restrict__ out)
{
    const int e    = blockIdx.x;
    const int tid  = threadIdx.x;
    const int wave = tid >> 6, lane = tid & 63;
    const int u    = lane >> 2;              // unit-local 0..15
    const int gate = lane & 3;
    const int j    = wave * 16 + u;          // unit 0..63
    const bool og  = (gate == 3);

    __shared__ __attribute__((aligned(16))) float lds[2 * PW];

    // ---- column weights: lane owns column (j, gate), all 130 k ----
    float wcol[130];
    #pragma unroll
    for (int k = 0; k < 130; ++k) wcol[k] = wrow(W, U, k, gate * 65 + j);
    // pin: opaque asm defines the live values; compiler cannot sink the loads
    #pragma unroll
    for (int k = 0; k < 130; ++k) { asm volatile("" : "+v"(wcol[k])); }

    const float breg = b[gate * 65 + j];
    const float sk   = (gate == 2) ? 2.0f : 1.0f;   // g-gate: tanh(z)=2*sig(2z)-1
    const float dk   = 1.0f - sk;

    // distributed read offset (words); lanes >=34 clamp to word 132 (harmless)
    const int rdoff = (lane < 34) ? 4 * lane : 132;

    // unit-64: wave m64+1 owns layer m64. Weights word-mapped to this lane's f4.
    const int m64 = (wave >= 1) ? (wave - 1) : 0;
    float w64w[4][4];                                 // [comp i][gate]
    #pragma unroll
    for (int i = 0; i < 4; ++i) {
        const int  wd  = rdoff + i;
        const bool val = (wave >= 1) && (lane < 34) &&
                         !(wd >= 65 && wd < 68) && (wd < 133);
        const int  k   = (wd < 65) ? wd : wd - 3;
        #pragma unroll
        for (int g = 0; g < 4; ++g)
            w64w[i][g] = val ? wrow(W, U, k, g * 65 + 64) : 0.0f;
    }
    const float b64i = b[64], b64f = b[129], b64g = b[194], b64o = b[259];

    float c_0 = 0, c_1 = 0, c_2 = 0, c64 = 0;

    const float* xrow = x   + (size_t)e * SEQ * UNITS;
    float*       orow = out + (size_t)e * SEQ * UNITS;

    // ---- init: zero LDS (pads + h-parts must be 0), write x(0), preload x(1) ----
    for (int i = tid; i < 2 * PW; i += 256) lds[i] = 0.0f;
    __syncthreads();
    if (wave == 0) {
        if (lane < 16) *(float4*)(lds + 4 * lane) = *(const float4*)(xrow + 4 * lane);
        if (lane == 16) lds[64] = xrow[64];
    }
    __syncthreads();
    float4 xq4 = {0,0,0,0}; float xqs = 0.0f;
    if (wave == 0) {
        if (lane < 16) xq4 = *(const float4*)(xrow + UNITS + 4 * lane);
        if (lane == 16) xqs = xrow[UNITS + 64];
    }

    int cur = 0;
    int s = 0;
    STEP(1, 0, 0); ++s;                    // s=0: layer0 only
    STEP(1, 1, 0); ++s;                    // s=1: layers 0,1
    for (; s < SEQ; ++s) { STEP(1, 1, 1); }
    STEP(0, 1, 1); ++s;                    // s=SEQ: layers 1,2
    STEP(0, 0, 1);                         // s=SEQ+1: layer 2 drains
}

// Dense head, in place on d_out: out_row = row @ Wd + bd. One thread per row.
__global__ __launch_bounds__(256)
void dense_kernel(float* __restrict__ io,
                  const float* __restrict__ Wd,
                  const float* __restrict__ bd)
{
    __shared__ __attribute__((aligned(16))) float wS[65 * 68];
    __shared__ float bS[65];
    for (int i = threadIdx.x; i < 65 * 65; i += 256) {
        int r = i / 65, c = i - r * 65;
        wS[r * 68 + c] = Wd[i];
    }
    if (threadIdx.x < 65) bS[threadIdx.x] = bd[threadIdx.x];
    __syncthreads();

    const size_t row  = (size_t)blockIdx.x * 256 + threadIdx.x;
    const size_t base = row * 65;

    float r[65];
    #pragma unroll
    for (int k = 0; k < 65; ++k) r[k] = io[base + k];

    for (int ct = 0; ct < 16; ++ct) {
        const int c = ct * 4;
        float a0 = bS[c], a1 = bS[c + 1], a2 = bS[c + 2], a3 = bS[c + 3];
        #pragma unroll
        for (int k = 0; k < 65; ++k) {
            const float4 wv = *reinterpret_cast<const float4*>(&wS[k * 68 + c]);
            a0 += r[k] * wv.x;
            a1 += r[k] * wv.y;
            a2 += r[k] * wv.z;
            a3 += r[k] * wv.w;
        }
        io[base + c]     = a0;
        io[base + c + 1] = a1;
        io[base + c + 2] = a2;
        io[base + c + 3] = a3;
    }
    float a = bS[64];
    #pragma unroll
    for (int k = 0; k < 65; ++k) a += r[k] * wS[k * 68 + 64];
    io[base + 64] = a;
}

extern "C" void kernel_launch(void* const* d_in, const int* in_sizes, int n_in,
                              void* d_out, int out_size, void* d_ws, size_t ws_size,
                              hipStream_t stream)
{
    const float* x  = (const float*)d_in[0];
    const float* W  = (const float*)d_in[1];
    const float* U  = (const float*)d_in[2];
    const float* b  = (const float*)d_in[3];
    const float* Wd = (const float*)d_in[4];
    const float* bd = (const float*)d_in[5];
    float* out = (float*)d_out;

    hipLaunchKernelGGL(lstm3_kernel, dim3(BATCH), dim3(256), 0, stream, x, W, U, b, out);
    hipLaunchKernelGGL(dense_kernel, dim3(1600), dim3(256), 0, stream, out, Wd, bd);
}